// Round 8
// baseline (186.148 us; speedup 1.0000x reference)
//
#include <hip/hip_runtime.h>
#include <math.h>

// Network_22892175688023 — round 8: 5 wide kernels (node count + kernel time co-minimized).
//   K1 k_prep_enc1 : E1/E2/E3 planes (448 blk) + Xs frags (64) + enc L1 VALU (64)
//   K2 k_enc2      : reduce slots1, bn1+relu, enc L2, slots2           (64 blk)
//   K3 k_gen1_gate : gen1 raw p[e] (512 blk) + gating MLP -> bcg (64 blk)
//   K4 k_gen2c     : inline comb1 (bc-blend+eb1+elu -> A1 frags LDS) + MFMA gen2 -> p2[e]  (64x8)
//   K5 k_gen3c     : inline comb2 -> A2 frags LDS + MFMA gen3 (waves split experts,
//                    bc folded) + LDS cross-wave reduce + eb3 blend -> out  (64 blk)

#define DIN 103
#define NE  8
#define HH  256
#define DOUT 51
#define EPSBN 1e-5f

typedef __attribute__((ext_vector_type(8))) short bf16x8;
typedef __attribute__((ext_vector_type(4))) float f32x4;
typedef __attribute__((ext_vector_type(8))) unsigned short us8;
typedef unsigned short ushort_t;

__device__ __forceinline__ float eluf(float v) { return v > 0.f ? v : (expf(v) - 1.f); }
__device__ __forceinline__ unsigned short bf16h(float f) {
  unsigned u = __float_as_uint(f);
  u += 0x7FFFu + ((u >> 16) & 1u);
  return (unsigned short)(u >> 16);
}
__device__ __forceinline__ float bf16f(unsigned short h) { return __uint_as_float(((unsigned)h) << 16); }
__device__ __forceinline__ void split_bf16(float v, unsigned short& h, unsigned short& l) {
  h = bf16h(v);
  l = bf16h(v - bf16f(h));
}
#define MFMA __builtin_amdgcn_mfma_f32_16x16x32_bf16

// ---- ws layout (float offsets) ----
#define O_SLOTS1 0        // [64][128]
#define O_SLOTS2 8192     // [64][64]
#define O_BCG    12288    // [1024][8]
#define O_H1RAW  20480    // [1024][64]
#define O_H2RAW  86016    // [1024][32]
#define O_XSH    118784   // [64 msub][4 kc][512] sh
#define O_XSL    184320
#define O_E1H    249856   // [8 e][16 ns][4 kc][512] sh
#define O_E1L    380928
#define O_E2H    512000   // [8 e][16 ns][8 kc][512] sh
#define O_E2L    774144
#define O_E3H    1036288  // [8 e][4 ns][8 kc][512] sh
#define O_E3L    1101824
#define O_P      1167360  // [8][1024][256] f32
#define O_P2     3264512  // [8][1024][256] f32

// ================= K1: prep planes + Xs frags + enc L1 (VALU) =================
// blocks: E2 0..255 | E1 256..383 | E3 384..447 | Xs 448..511 | enc1 512..575
__global__ __launch_bounds__(256) void k_prep_enc1(
    const float* __restrict__ x, const float* __restrict__ w1, const float* __restrict__ b1,
    const float* __restrict__ ew1, const float* __restrict__ ew2, const float* __restrict__ ew3,
    float* __restrict__ ws) {
  __shared__ float tile[32][65];
  __shared__ float w1L[64 * DIN];
  __shared__ float xr16[16][104];
  __shared__ float hb[16][64];
  int bk = blockIdx.x, t = threadIdx.x;
  int l2 = t & 63, c = l2 & 15, q = l2 >> 4;

  if (bk < 256) {          // ---- E2: K=256, N=256 ----
    int nh = bk & 3, kc = (bk >> 2) & 7, e = bk >> 5;
    int k0 = kc * 32, n0 = nh * 64;
#pragma unroll
    for (int i = 0; i < 8; ++i) {
      int kl = (t >> 6) + i * 4;
      tile[kl][t & 63] = ew2[((size_t)e * HH + k0 + kl) * HH + n0 + (t & 63)];
    }
    __syncthreads();
    int nsl = t >> 6;
    us8 H8, L8;
#pragma unroll
    for (int j = 0; j < 8; ++j) {
      unsigned short h, lo; split_bf16(tile[q * 8 + j][nsl * 16 + c], h, lo);
      H8[j] = h; L8[j] = lo;
    }
    size_t dst = (((size_t)(e * 16 + nh * 4 + nsl)) * 8 + kc) * 512 + l2 * 8;
    *(us8*)((ushort_t*)(ws + O_E2H) + dst) = H8;
    *(us8*)((ushort_t*)(ws + O_E2L) + dst) = L8;
  } else if (bk < 384) {   // ---- E1: K=103->128, N=256 ----
    int b2 = bk - 256;
    int nh = b2 & 3, kc = (b2 >> 2) & 3, e = b2 >> 4;
    int k0 = kc * 32, n0 = nh * 64;
#pragma unroll
    for (int i = 0; i < 8; ++i) {
      int kl = (t >> 6) + i * 4;
      int k = k0 + kl;
      tile[kl][t & 63] = (k < DIN) ? ew1[((size_t)e * DIN + k) * HH + n0 + (t & 63)] : 0.f;
    }
    __syncthreads();
    int nsl = t >> 6;
    us8 H8, L8;
#pragma unroll
    for (int j = 0; j < 8; ++j) {
      unsigned short h, lo; split_bf16(tile[q * 8 + j][nsl * 16 + c], h, lo);
      H8[j] = h; L8[j] = lo;
    }
    size_t dst = (((size_t)(e * 16 + nh * 4 + nsl)) * 4 + kc) * 512 + l2 * 8;
    *(us8*)((ushort_t*)(ws + O_E1H) + dst) = H8;
    *(us8*)((ushort_t*)(ws + O_E1L) + dst) = L8;
  } else if (bk < 448) {   // ---- E3: K=256, N=51->64 ----
    int b2 = bk - 384;
    int kc = b2 & 7, e = b2 >> 3;
    int k0 = kc * 32;
#pragma unroll
    for (int i = 0; i < 8; ++i) {
      int kl = (t >> 6) + i * 4;
      int n = t & 63;
      tile[kl][n] = (n < DOUT) ? ew3[((size_t)e * HH + k0 + kl) * DOUT + n] : 0.f;
    }
    __syncthreads();
    int nsl = t >> 6;
    us8 H8, L8;
#pragma unroll
    for (int j = 0; j < 8; ++j) {
      unsigned short h, lo; split_bf16(tile[q * 8 + j][nsl * 16 + c], h, lo);
      H8[j] = h; L8[j] = lo;
    }
    size_t dst = (((size_t)(e * 4 + nsl)) * 8 + kc) * 512 + l2 * 8;
    *(us8*)((ushort_t*)(ws + O_E3H) + dst) = H8;
    *(us8*)((ushort_t*)(ws + O_E3L) + dst) = L8;
  } else if (bk < 512) {   // ---- Xs: A-fragments of scaled x, 16 rows/block ----
    int msub = bk - 448;
    for (int i = t; i < 16 * 104; i += 256) {
      int b = i / 104, k = i - b * 104;
      float v = 0.f;
      if (k < DIN) { v = x[(size_t)(msub * 16 + b) * DIN + k]; if (k >= 100) v *= 100.f; }
      xr16[b][k] = v;
    }
    __syncthreads();
    int kc = t >> 6;
    us8 H8, L8;
#pragma unroll
    for (int j = 0; j < 8; ++j) {
      int k = kc * 32 + q * 8 + j;
      float v = (k < 104) ? xr16[c][k] : 0.f;
      unsigned short h, lo; split_bf16(v, h, lo);
      H8[j] = h; L8[j] = lo;
    }
    size_t dst = ((size_t)msub * 4 + kc) * 512 + l2 * 8;
    *(us8*)((ushort_t*)(ws + O_XSH) + dst) = H8;
    *(us8*)((ushort_t*)(ws + O_XSL) + dst) = L8;
  } else {                 // ---- enc L1 (VALU): 16 rows/block ----
    float* slots1 = ws + O_SLOTS1;
    float* h1raw  = ws + O_H1RAW;
    int bkl = bk - 512;
    int r0 = bkl * 16;
    for (int i = t; i < 64 * DIN; i += 256) w1L[i] = w1[i];
    for (int i = t; i < 16 * 104; i += 256) {
      int r = i / 104, c2 = i - r * 104;
      float v = 0.f;
      if (c2 < DIN) { v = x[(size_t)(r0 + r) * DIN + c2]; if (c2 >= 100) v *= 100.f; }
      xr16[r][c2] = v;
    }
    __syncthreads();
#pragma unroll
    for (int i = 0; i < 4; ++i) {
      int idx = t + i * 256;
      int r = idx >> 6, j = idx & 63;
      float acc = b1[j];
      for (int k = 0; k < DIN; ++k) acc = fmaf(xr16[r][k], w1L[j * DIN + k], acc);
      hb[r][j] = acc;
      h1raw[(size_t)(r0 + r) * 64 + j] = acc;
    }
    __syncthreads();
    if (t < 64) {
      float s = 0.f, qq = 0.f;
      for (int r = 0; r < 16; ++r) { float v = hb[r][t]; s += v; qq += v * v; }
      slots1[bkl * 128 + t] = s;
      slots1[bkl * 128 + 64 + t] = qq;
    }
  }
}

// ================= K2: reduce stats1, bn1+relu, enc L2 (VALU), slots2 =================
__global__ __launch_bounds__(256) void k_enc2(
    const float* __restrict__ gamma1, const float* __restrict__ beta1,
    const float* __restrict__ w2, const float* __restrict__ b2, float* __restrict__ ws) {
  __shared__ float w2T[64 * 33];
  __shared__ float red[128];
  __shared__ float sc1[64], sh1[64];
  __shared__ float h1b[16][64];
  __shared__ float hb2[16][32];
  float* slots1 = ws + O_SLOTS1;
  float* slots2 = ws + O_SLOTS2;
  float* h1raw  = ws + O_H1RAW;
  float* h2raw  = ws + O_H2RAW;
  int bk = blockIdx.x, t = threadIdx.x;
  int R0 = bk * 16;
  for (int i = t; i < 2048; i += 256) { int j = i >> 6, k = i & 63; w2T[k * 33 + j] = w2[i]; }
  if (t < 128) {
    float s = 0.f;
    for (int b = 0; b < 64; ++b) s += slots1[b * 128 + t];
    red[t] = s;
  }
  __syncthreads();
  if (t < 64) {
    float m = red[t] * (1.f / 1024.f);
    float v = red[64 + t] * (1.f / 1024.f) - m * m;
    float sc = gamma1[t] * rsqrtf(v + EPSBN);
    sc1[t] = sc; sh1[t] = beta1[t] - m * sc;
  }
  __syncthreads();
#pragma unroll
  for (int i = 0; i < 4; ++i) {
    int idx = t + i * 256;
    int r = idx >> 6, k = idx & 63;
    h1b[r][k] = fmaxf(fmaf(h1raw[(size_t)(R0 + r) * 64 + k], sc1[k], sh1[k]), 0.f);
  }
  __syncthreads();
#pragma unroll
  for (int i = 0; i < 2; ++i) {
    int o = t + i * 256;
    int r = o >> 5, j = o & 31;
    float acc = b2[j];
    for (int k = 0; k < 64; ++k) acc = fmaf(h1b[r][k], w2T[k * 33 + j], acc);
    hb2[r][j] = acc;
    h2raw[(size_t)(R0 + r) * 32 + j] = acc;
  }
  __syncthreads();
  if (t < 32) {
    float s = 0.f, q = 0.f;
    for (int r = 0; r < 16; ++r) { float v = hb2[r][t]; s += v; q += v * v; }
    slots2[bk * 64 + t] = s;
    slots2[bk * 64 + 32 + t] = q;
  }
}

// ================= K3: gen1 raw p[e] (blocks 0-511) + gating -> bcg (512-575) =================
__global__ __launch_bounds__(256) void k_gen1_gate(
    const float* __restrict__ gamma2, const float* __restrict__ beta2,
    const float* __restrict__ gw1, const float* __restrict__ gb1,
    const float* __restrict__ gw2, const float* __restrict__ gb2,
    const float* __restrict__ gw3, const float* __restrict__ gb3,
    float* __restrict__ ws) {
  int blk = blockIdx.x, t = threadIdx.x;
  int wv = t >> 6, l = t & 63;
  if (blk < 512) {          // ---- gen1: p[e] = xs @ ew1_e ----
    int bk = blk >> 3, e = blk & 7;
    int c = l & 15, quad = l >> 4;
    const ushort_t* XsH = (const ushort_t*)(ws + O_XSH);
    const ushort_t* XsL = (const ushort_t*)(ws + O_XSL);
    const ushort_t* E1H = (const ushort_t*)(ws + O_E1H);
    const ushort_t* E1L = (const ushort_t*)(ws + O_E1L);
    float* p = ws + O_P;
    f32x4 acc[4] = {};
#pragma unroll
    for (int kc = 0; kc < 4; ++kc) {
      bf16x8 ah = *(const bf16x8*)(XsH + ((size_t)bk * 4 + kc) * 512 + l * 8);
      bf16x8 al = *(const bf16x8*)(XsL + ((size_t)bk * 4 + kc) * 512 + l * 8);
#pragma unroll
      for (int nsi = 0; nsi < 4; ++nsi) {
        int ns = wv * 4 + nsi;
        size_t bo = (((size_t)(e * 16 + ns)) * 4 + kc) * 512 + l * 8;
        bf16x8 bh = *(const bf16x8*)(E1H + bo);
        bf16x8 bl = *(const bf16x8*)(E1L + bo);
        acc[nsi] = MFMA(ah, bh, acc[nsi], 0, 0, 0);
        acc[nsi] = MFMA(al, bh, acc[nsi], 0, 0, 0);
        acc[nsi] = MFMA(ah, bl, acc[nsi], 0, 0, 0);
      }
    }
    float* pe = p + (size_t)e * 262144;
#pragma unroll
    for (int nsi = 0; nsi < 4; ++nsi) {
      int col = (wv * 4 + nsi) * 16 + c;
#pragma unroll
      for (int r = 0; r < 4; ++r)
        pe[(size_t)(bk * 16 + quad * 4 + r) * 256 + col] = acc[nsi][r];
    }
  } else {                  // ---- gate: bn2 + gating MLP -> bcg ----
    __shared__ float red2[64], sc2[32], sh2[32];
    __shared__ float lat[16][32];
    __shared__ float gw1L[64 * 33], gw2L[64 * 65], gw3L[8 * 65];
    __shared__ float gb1L[64], gb2L[64], gb3L[8];
    __shared__ float g1[16][64], g2[16][64];
    float* slots2 = ws + O_SLOTS2;
    float* bcg    = ws + O_BCG;
    float* h2raw  = ws + O_H2RAW;
    int bk = blk - 512;
    int R0 = bk * 16;
    for (int i = t; i < 2048; i += 256) { int j = i >> 5, k = i & 31; gw1L[j * 33 + k] = gw1[i]; }
    for (int i = t; i < 4096; i += 256) { int j = i >> 6, k = i & 63; gw2L[j * 65 + k] = gw2[i]; }
    for (int i = t; i < 512; i += 256) { int j = i >> 6, k = i & 63; gw3L[j * 65 + k] = gw3[i]; }
    if (t < 64) { gb1L[t] = gb1[t]; gb2L[t] = gb2[t]; }
    if (t < 8) gb3L[t] = gb3[t];
    if (t < 64) {
      float s = 0.f;
      for (int b = 0; b < 64; ++b) s += slots2[b * 64 + t];
      red2[t] = s;
    }
    __syncthreads();
    if (t < 32) {
      float m = red2[t] * (1.f / 1024.f);
      float v = red2[32 + t] * (1.f / 1024.f) - m * m;
      float sc = gamma2[t] * rsqrtf(v + EPSBN);
      sc2[t] = sc; sh2[t] = beta2[t] - m * sc;
    }
    __syncthreads();
#pragma unroll
    for (int i = 0; i < 2; ++i) {
      int idx = t + i * 256;
      int r = idx >> 5, cc = idx & 31;
      lat[r][cc] = fmaxf(fmaf(h2raw[(size_t)(R0 + r) * 32 + cc], sc2[cc], sh2[cc]), 0.f);
    }
    __syncthreads();
#pragma unroll
    for (int rr = 0; rr < 4; ++rr) {
      int r = wv * 4 + rr;
      float a1 = gb1L[l];
      for (int k = 0; k < 32; ++k) a1 = fmaf(gw1L[l * 33 + k], lat[r][k], a1);
      g1[r][l] = eluf(a1);
    }
    __syncthreads();
#pragma unroll
    for (int rr = 0; rr < 4; ++rr) {
      int r = wv * 4 + rr;
      float a2 = gb2L[l];
      for (int k = 0; k < 64; ++k) a2 = fmaf(gw2L[l * 65 + k], g1[r][k], a2);
      g2[r][l] = eluf(a2);
    }
    __syncthreads();
#pragma unroll
    for (int rr = 0; rr < 4; ++rr) {
      int r = wv * 4 + rr;
      if (l < 8) {
        float a3 = gb3L[l];
        for (int k = 0; k < 64; ++k) a3 = fmaf(gw3L[l * 65 + k], g2[r][k], a3);
        float mx = a3;
        mx = fmaxf(mx, __shfl_xor(mx, 1));
        mx = fmaxf(mx, __shfl_xor(mx, 2));
        mx = fmaxf(mx, __shfl_xor(mx, 4));
        float p = expf(a3 - mx);
        float sp = p;
        sp += __shfl_xor(sp, 1); sp += __shfl_xor(sp, 2); sp += __shfl_xor(sp, 4);
        bcg[(size_t)(R0 + r) * 8 + l] = p / sp;
      }
    }
  }
}

// ================= K4: inline comb1 -> A1 frags LDS, MFMA gen2 -> p2[e]  (grid 64 x 8) =================
__global__ __launch_bounds__(256) void k_gen2c(const float* __restrict__ eb1, float* __restrict__ ws) {
  __shared__ __attribute__((aligned(16))) unsigned short aHs[4096], aLs[4096];
  int bk = blockIdx.x, e = blockIdx.y, t = threadIdx.x;
  int wv = t >> 6, l = t & 63, c = l & 15, quad = l >> 4;
  int R0 = bk * 16;
  const float* P   = ws + O_P;
  const float* bcg = ws + O_BCG;
  const ushort_t* E2H = (const ushort_t*)(ws + O_E2H);
  const ushort_t* E2L = (const ushort_t*)(ws + O_E2L);
  float* P2 = ws + O_P2;
  // inline comb1: A1 = elu(sum_e bc*(p+eb1)) -> fragment-order LDS
#pragma unroll
  for (int i = 0; i < 2; ++i) {
    int idx = t + i * 256;                 // [0,512) slots: [8 kc][64 l2]
    int kc = idx >> 6, l2 = idx & 63;
    int b = R0 + (l2 & 15);
    int k0 = kc * 32 + (l2 >> 4) * 8;
    float s[8] = {};
#pragma unroll
    for (int e2 = 0; e2 < 8; ++e2) {
      float w8 = bcg[b * 8 + e2];
      const float* pr = P + (size_t)e2 * 262144 + (size_t)b * 256 + k0;
      float4 p0 = *(const float4*)pr, p1 = *(const float4*)(pr + 4);
      const float* er = eb1 + e2 * 256 + k0;
      float4 e0 = *(const float4*)er, e1 = *(const float4*)(er + 4);
      s[0] = fmaf(w8, p0.x + e0.x, s[0]);
      s[1] = fmaf(w8, p0.y + e0.y, s[1]);
      s[2] = fmaf(w8, p0.z + e0.z, s[2]);
      s[3] = fmaf(w8, p0.w + e0.w, s[3]);
      s[4] = fmaf(w8, p1.x + e1.x, s[4]);
      s[5] = fmaf(w8, p1.y + e1.y, s[5]);
      s[6] = fmaf(w8, p1.z + e1.z, s[6]);
      s[7] = fmaf(w8, p1.w + e1.w, s[7]);
    }
    us8 H, L;
#pragma unroll
    for (int j = 0; j < 8; ++j) {
      float v = eluf(s[j]);
      unsigned short h, lo; split_bf16(v, h, lo);
      H[j] = h; L[j] = lo;
    }
    *(us8*)(aHs + idx * 8) = H;
    *(us8*)(aLs + idx * 8) = L;
  }
  __syncthreads();
  bf16x8 ah[8], al[8];
#pragma unroll
  for (int kc = 0; kc < 8; ++kc) {
    ah[kc] = *(const bf16x8*)(aHs + kc * 512 + l * 8);
    al[kc] = *(const bf16x8*)(aLs + kc * 512 + l * 8);
  }
  f32x4 acc[4] = {};
#pragma unroll
  for (int kc = 0; kc < 8; ++kc) {
#pragma unroll
    for (int nsi = 0; nsi < 4; ++nsi) {
      int ns = wv * 4 + nsi;
      size_t bo = (((size_t)(e * 16 + ns)) * 8 + kc) * 512 + l * 8;
      bf16x8 bh = *(const bf16x8*)(E2H + bo);
      bf16x8 bl = *(const bf16x8*)(E2L + bo);
      acc[nsi] = MFMA(ah[kc], bh, acc[nsi], 0, 0, 0);
      acc[nsi] = MFMA(al[kc], bh, acc[nsi], 0, 0, 0);
      acc[nsi] = MFMA(ah[kc], bl, acc[nsi], 0, 0, 0);
    }
  }
  float* pe = P2 + (size_t)e * 262144;
#pragma unroll
  for (int nsi = 0; nsi < 4; ++nsi) {
    int col = (wv * 4 + nsi) * 16 + c;
#pragma unroll
    for (int r = 0; r < 4; ++r)
      pe[(size_t)(bk * 16 + quad * 4 + r) * 256 + col] = acc[nsi][r];
  }
}

// ================= K5: inline comb2 + MFMA gen3 (waves split experts) + reduce -> out =================
__global__ __launch_bounds__(256) void k_gen3c(const float* __restrict__ eb2,
    const float* __restrict__ eb3, float* __restrict__ ws, float* __restrict__ out) {
  __shared__ __attribute__((aligned(16))) unsigned short aHs[4096], aLs[4096];
  __shared__ float bcL[16][8];
  __shared__ float eb3L[8][64];
  __shared__ float p3s[4][16][64];
  int bk = blockIdx.x, t = threadIdx.x;
  int wv = t >> 6, l = t & 63, c = l & 15, quad = l >> 4;
  int R0 = bk * 16;
  const float* P2  = ws + O_P2;
  const float* bcg = ws + O_BCG;
  const ushort_t* E3H = (const ushort_t*)(ws + O_E3H);
  const ushort_t* E3L = (const ushort_t*)(ws + O_E3L);
  if (t < 128) bcL[t >> 3][t & 7] = bcg[(size_t)(R0 + (t >> 3)) * 8 + (t & 7)];
  for (int i = t; i < 512; i += 256) {
    int e = i >> 6, n = i & 63;
    eb3L[e][n] = (n < DOUT) ? eb3[e * DOUT + n] : 0.f;
  }
  // inline comb2 -> A2 fragments in LDS
#pragma unroll
  for (int i = 0; i < 2; ++i) {
    int idx = t + i * 256;
    int kc = idx >> 6, l2 = idx & 63;
    int b = R0 + (l2 & 15);
    int k0 = kc * 32 + (l2 >> 4) * 8;
    float s[8] = {};
#pragma unroll
    for (int e2 = 0; e2 < 8; ++e2) {
      float w8 = bcg[b * 8 + e2];
      const float* pr = P2 + (size_t)e2 * 262144 + (size_t)b * 256 + k0;
      float4 p0 = *(const float4*)pr, p1 = *(const float4*)(pr + 4);
      const float* er = eb2 + e2 * 256 + k0;
      float4 e0 = *(const float4*)er, e1 = *(const float4*)(er + 4);
      s[0] = fmaf(w8, p0.x + e0.x, s[0]);
      s[1] = fmaf(w8, p0.y + e0.y, s[1]);
      s[2] = fmaf(w8, p0.z + e0.z, s[2]);
      s[3] = fmaf(w8, p0.w + e0.w, s[3]);
      s[4] = fmaf(w8, p1.x + e1.x, s[4]);
      s[5] = fmaf(w8, p1.y + e1.y, s[5]);
      s[6] = fmaf(w8, p1.z + e1.z, s[6]);
      s[7] = fmaf(w8, p1.w + e1.w, s[7]);
    }
    us8 H, L;
#pragma unroll
    for (int j = 0; j < 8; ++j) {
      float v = eluf(s[j]);
      unsigned short h, lo; split_bf16(v, h, lo);
      H[j] = h; L[j] = lo;
    }
    *(us8*)(aHs + idx * 8) = H;
    *(us8*)(aLs + idx * 8) = L;
  }
  __syncthreads();
  bf16x8 ah[8], al[8];
#pragma unroll
  for (int kc = 0; kc < 8; ++kc) {
    ah[kc] = *(const bf16x8*)(aHs + kc * 512 + l * 8);
    al[kc] = *(const bf16x8*)(aLs + kc * 512 + l * 8);
  }
  f32x4 tot[4] = {};
#pragma unroll
  for (int ei = 0; ei < 2; ++ei) {
    int e = wv * 2 + ei;
#pragma unroll
    for (int nsi = 0; nsi < 4; ++nsi) {
      f32x4 acc = {0.f, 0.f, 0.f, 0.f};
#pragma unroll
      for (int kc = 0; kc < 8; ++kc) {
        size_t bo = (((size_t)(e * 4 + nsi)) * 8 + kc) * 512 + l * 8;
        bf16x8 bh = *(const bf16x8*)(E3H + bo);
        bf16x8 bl = *(const bf16x8*)(E3L + bo);
        acc = MFMA(ah[kc], bh, acc, 0, 0, 0);
        acc = MFMA(al[kc], bh, acc, 0, 0, 0);
        acc = MFMA(ah[kc], bl, acc, 0, 0, 0);
      }
#pragma unroll
      for (int r = 0; r < 4; ++r)
        tot[nsi][r] = fmaf(bcL[quad * 4 + r][e], acc[r], tot[nsi][r]);
    }
  }
#pragma unroll
  for (int nsi = 0; nsi < 4; ++nsi)
#pragma unroll
    for (int r = 0; r < 4; ++r)
      p3s[wv][quad * 4 + r][nsi * 16 + c] = tot[nsi][r];
  __syncthreads();
#pragma unroll
  for (int i = 0; i < 4; ++i) {
    int idx = t + i * 256;
    int row = idx >> 6, col = idx & 63;
    float s = p3s[0][row][col] + p3s[1][row][col] + p3s[2][row][col] + p3s[3][row][col];
    float bb = 0.f;
#pragma unroll
    for (int e = 0; e < 8; ++e) bb = fmaf(bcL[row][e], eb3L[e][col], bb);
    if (col < DOUT) out[(size_t)(R0 + row) * DOUT + col] = s + bb;
  }
}

extern "C" void kernel_launch(void* const* d_in, const int* in_sizes, int n_in,
                              void* d_out, int out_size, void* d_ws, size_t ws_size,
                              hipStream_t stream) {
  const float* x      = (const float*)d_in[0];
  const float* w1     = (const float*)d_in[1];
  const float* b1     = (const float*)d_in[2];
  const float* gamma1 = (const float*)d_in[3];
  const float* beta1  = (const float*)d_in[4];
  const float* w2     = (const float*)d_in[5];
  const float* b2     = (const float*)d_in[6];
  const float* gamma2 = (const float*)d_in[7];
  const float* beta2  = (const float*)d_in[8];
  const float* gw1    = (const float*)d_in[9];
  const float* gb1    = (const float*)d_in[10];
  const float* gw2    = (const float*)d_in[11];
  const float* gb2    = (const float*)d_in[12];
  const float* gw3    = (const float*)d_in[13];
  const float* gb3    = (const float*)d_in[14];
  const float* ew1    = (const float*)d_in[15];
  const float* eb1    = (const float*)d_in[16];
  const float* ew2    = (const float*)d_in[17];
  const float* eb2    = (const float*)d_in[18];
  const float* ew3    = (const float*)d_in[19];
  const float* eb3    = (const float*)d_in[20];
  float* wsf  = (float*)d_ws;
  float* outp = (float*)d_out;

  k_prep_enc1<<<576, 256, 0, stream>>>(x, w1, b1, ew1, ew2, ew3, wsf);
  k_enc2<<<64, 256, 0, stream>>>(gamma1, beta1, w2, b2, wsf);
  k_gen1_gate<<<576, 256, 0, stream>>>(gamma2, beta2, gw1, gb1, gw2, gb2, gw3, gb3, wsf);
  k_gen2c<<<dim3(64, 8), 256, 0, stream>>>(eb1, wsf);
  k_gen3c<<<64, 256, 0, stream>>>(eb2, eb3, wsf, outp);
}

// Round 9
// 160.064 us; speedup vs baseline: 1.1630x; 1.1630x over previous
//
#include <hip/hip_runtime.h>
#include <math.h>

// Network_22892175688023 — round 9: R7 structure (verified 166.7us) + B-hi-only for
// layers 2/3 (drop aH*bL MFMA there; E2/E3 lo-planes not built). gen1 keeps bf16x3
// (x has *100-scaled columns). R8's merges regressed (-width, +redundancy) — reverted.
//   k_prep  : operand planes (E1 hi+lo, E2/E3 hi only, W1 hi+lo, Xs hi+lo)
//   k_enc1  : MFMA h1raw = xs@w1^T + b1 + stat slots                  (64 blk)
//   k_enc2  : reduce slots1, bn1+relu, enc L2, slots2                 (64 blk)
//   k_gate  : reduce slots2, bn2, gating MLP -> bc                    (64 blk)
//   k_gen1  : p[e] = xs @ ew1_e                                       (64x8 blk)
//   k_comb1 : A1 = elu(sum_e bc*(p+eb1)) -> fragment planes           (128 blk)
//   k_gen2  : p[e] = a1 @ ew2_e   (B hi only)                         (64x8 blk)
//   k_comb2 : A2 planes                                               (128 blk)
//   k_gen3  : p3[e] = a2 @ ew3_e  (B hi only)                         (64x2 blk)
//   k_comb3 : out = sum_e bc*(p3+eb3)                                 (256 blk)

#define DIN 103
#define NE  8
#define HH  256
#define DOUT 51
#define EPSBN 1e-5f

typedef __attribute__((ext_vector_type(8))) short bf16x8;
typedef __attribute__((ext_vector_type(4))) float f32x4;
typedef __attribute__((ext_vector_type(8))) unsigned short us8;
typedef unsigned short ushort_t;

__device__ __forceinline__ float eluf(float v) { return v > 0.f ? v : (expf(v) - 1.f); }
__device__ __forceinline__ unsigned short bf16h(float f) {
  unsigned u = __float_as_uint(f);
  u += 0x7FFFu + ((u >> 16) & 1u);
  return (unsigned short)(u >> 16);
}
__device__ __forceinline__ float bf16f(unsigned short h) { return __uint_as_float(((unsigned)h) << 16); }
__device__ __forceinline__ void split_bf16(float v, unsigned short& h, unsigned short& l) {
  h = bf16h(v);
  l = bf16h(v - bf16f(h));
}
#define MFMA __builtin_amdgcn_mfma_f32_16x16x32_bf16

// ---- ws layout (float offsets) ----
#define O_SLOTS1 0        // [64][128]
#define O_SLOTS2 8192     // [64][64]
#define O_BCG    12288    // [1024][8]
#define O_H1RAW  20480    // [1024][64]
#define O_H2RAW  86016    // [1024][32]
#define O_XSH    118784   // [64 msub][4 kc][512] sh
#define O_XSL    184320
#define O_W1H    249856   // [4 ns][4 kc][512] sh
#define O_W1L    253952
#define O_E1H    258048   // [8 e][16 ns][4 kc][512] sh
#define O_E1L    389120
#define O_E2H    520192   // [8 e][16 ns][8 kc][512] sh  (hi only)
#define O_E3H    782336   // [8 e][4 ns][8 kc][512] sh   (hi only)
#define O_A1H    847872   // [64 msub][8 kc][512] sh
#define O_A1L    978944
#define O_A2H    1110016
#define O_A2L    1241088
#define O_P      1372160  // [8][1024][256] f32 (p3 reuses as [8][1024][64])

// ================= prep: coalesced reads -> LDS tile -> fragment planes =================
// blocks: E2 0..255 | E1 256..383 | E3 384..447 | W1 448..451 | Xs 452..515
__global__ __launch_bounds__(256) void k_prep(
    const float* __restrict__ x, const float* __restrict__ w1,
    const float* __restrict__ ew1, const float* __restrict__ ew2, const float* __restrict__ ew3,
    float* __restrict__ ws) {
  __shared__ float tile[32][65];
  int bk = blockIdx.x, t = threadIdx.x;
  int l2 = t & 63, c = l2 & 15, q = l2 >> 4;

  if (bk < 256) {          // ---- E2: K=256, N=256, hi only ----
    int nh = bk & 3, kc = (bk >> 2) & 7, e = bk >> 5;
    int k0 = kc * 32, n0 = nh * 64;
#pragma unroll
    for (int i = 0; i < 8; ++i) {
      int kl = (t >> 6) + i * 4;
      tile[kl][t & 63] = ew2[((size_t)e * HH + k0 + kl) * HH + n0 + (t & 63)];
    }
    __syncthreads();
    int nsl = t >> 6;
    us8 H8;
#pragma unroll
    for (int j = 0; j < 8; ++j) H8[j] = bf16h(tile[q * 8 + j][nsl * 16 + c]);
    size_t dst = (((size_t)(e * 16 + nh * 4 + nsl)) * 8 + kc) * 512 + l2 * 8;
    *(us8*)((ushort_t*)(ws + O_E2H) + dst) = H8;
  } else if (bk < 384) {   // ---- E1: K=103->128, N=256, hi+lo ----
    int b2 = bk - 256;
    int nh = b2 & 3, kc = (b2 >> 2) & 3, e = b2 >> 4;
    int k0 = kc * 32, n0 = nh * 64;
#pragma unroll
    for (int i = 0; i < 8; ++i) {
      int kl = (t >> 6) + i * 4;
      int k = k0 + kl;
      tile[kl][t & 63] = (k < DIN) ? ew1[((size_t)e * DIN + k) * HH + n0 + (t & 63)] : 0.f;
    }
    __syncthreads();
    int nsl = t >> 6;
    us8 H8, L8;
#pragma unroll
    for (int j = 0; j < 8; ++j) {
      unsigned short h, lo; split_bf16(tile[q * 8 + j][nsl * 16 + c], h, lo);
      H8[j] = h; L8[j] = lo;
    }
    size_t dst = (((size_t)(e * 16 + nh * 4 + nsl)) * 4 + kc) * 512 + l2 * 8;
    *(us8*)((ushort_t*)(ws + O_E1H) + dst) = H8;
    *(us8*)((ushort_t*)(ws + O_E1L) + dst) = L8;
  } else if (bk < 448) {   // ---- E3: K=256, N=51->64, hi only ----
    int b2 = bk - 384;
    int kc = b2 & 7, e = b2 >> 3;
    int k0 = kc * 32;
#pragma unroll
    for (int i = 0; i < 8; ++i) {
      int kl = (t >> 6) + i * 4;
      int n = t & 63;
      tile[kl][n] = (n < DOUT) ? ew3[((size_t)e * HH + k0 + kl) * DOUT + n] : 0.f;
    }
    __syncthreads();
    int nsl = t >> 6;
    us8 H8;
#pragma unroll
    for (int j = 0; j < 8; ++j) H8[j] = bf16h(tile[q * 8 + j][nsl * 16 + c]);
    size_t dst = (((size_t)(e * 4 + nsl)) * 8 + kc) * 512 + l2 * 8;
    *(us8*)((ushort_t*)(ws + O_E3H) + dst) = H8;
  } else if (bk < 452) {   // ---- W1: B[k][n=j] from w1[j][k], hi+lo ----
    int kc = bk - 448;
    int k0 = kc * 32;
    __shared__ float tw[64][33];
#pragma unroll
    for (int p8 = 0; p8 < 8; ++p8) {
      int j = (t >> 5) + p8 * 8;
      int kl = t & 31;
      int k = k0 + kl;
      tw[j][kl] = (k < DIN) ? w1[(size_t)j * DIN + k] : 0.f;
    }
    __syncthreads();
    int nsl = t >> 6;
    us8 H8, L8;
#pragma unroll
    for (int j = 0; j < 8; ++j) {
      unsigned short h, lo; split_bf16(tw[nsl * 16 + c][q * 8 + j], h, lo);
      H8[j] = h; L8[j] = lo;
    }
    size_t dst = ((size_t)nsl * 4 + kc) * 512 + l2 * 8;
    *(us8*)((ushort_t*)(ws + O_W1H) + dst) = H8;
    *(us8*)((ushort_t*)(ws + O_W1L) + dst) = L8;
  } else {                 // ---- Xs: A-fragments of scaled x, 16 rows/block, hi+lo ----
    int msub = bk - 452;
    __shared__ float xt[16][104];
    for (int i = t; i < 16 * 104; i += 256) {
      int b = i / 104, k = i - b * 104;
      float v = 0.f;
      if (k < DIN) { v = x[(size_t)(msub * 16 + b) * DIN + k]; if (k >= 100) v *= 100.f; }
      xt[b][k] = v;
    }
    __syncthreads();
    int kc = t >> 6;
    int m = c;
    us8 H8, L8;
#pragma unroll
    for (int j = 0; j < 8; ++j) {
      int k = kc * 32 + q * 8 + j;
      float v = (k < 104) ? xt[m][k] : 0.f;
      unsigned short h, lo; split_bf16(v, h, lo);
      H8[j] = h; L8[j] = lo;
    }
    size_t dst = ((size_t)msub * 4 + kc) * 512 + l2 * 8;
    *(us8*)((ushort_t*)(ws + O_XSH) + dst) = H8;
    *(us8*)((ushort_t*)(ws + O_XSL) + dst) = L8;
  }
}

// ================= enc1: MFMA h1raw = xs@w1^T + b1, stat slots =================
__global__ __launch_bounds__(256) void k_enc1(const float* __restrict__ b1, float* __restrict__ ws) {
  __shared__ float tile[16][65];
  int bk = blockIdx.x, t = threadIdx.x;
  int wv = t >> 6, l = t & 63, c = l & 15, quad = l >> 4;
  const ushort_t* XsH = (const ushort_t*)(ws + O_XSH);
  const ushort_t* XsL = (const ushort_t*)(ws + O_XSL);
  const ushort_t* W1H = (const ushort_t*)(ws + O_W1H);
  const ushort_t* W1L = (const ushort_t*)(ws + O_W1L);
  float* h1raw  = ws + O_H1RAW;
  float* slots1 = ws + O_SLOTS1;
  f32x4 acc = {0.f, 0.f, 0.f, 0.f};
#pragma unroll
  for (int kc = 0; kc < 4; ++kc) {
    bf16x8 ah = *(const bf16x8*)(XsH + ((size_t)bk * 4 + kc) * 512 + l * 8);
    bf16x8 al = *(const bf16x8*)(XsL + ((size_t)bk * 4 + kc) * 512 + l * 8);
    bf16x8 bh = *(const bf16x8*)(W1H + ((size_t)wv * 4 + kc) * 512 + l * 8);
    bf16x8 bl = *(const bf16x8*)(W1L + ((size_t)wv * 4 + kc) * 512 + l * 8);
    acc = MFMA(ah, bh, acc, 0, 0, 0);
    acc = MFMA(al, bh, acc, 0, 0, 0);
    acc = MFMA(ah, bl, acc, 0, 0, 0);
  }
  int col = wv * 16 + c;
  float b1v = b1[col];
#pragma unroll
  for (int r = 0; r < 4; ++r) {
    float v = acc[r] + b1v;
    tile[quad * 4 + r][col] = v;
    h1raw[(size_t)(bk * 16 + quad * 4 + r) * 64 + col] = v;
  }
  __syncthreads();
  if (t < 64) {
    float s = 0.f, qq = 0.f;
    for (int r = 0; r < 16; ++r) { float v = tile[r][t]; s += v; qq += v * v; }
    slots1[bk * 128 + t] = s;
    slots1[bk * 128 + 64 + t] = qq;
  }
}

// ================= enc2: reduce stats1, bn1+relu, enc L2 (VALU), slots2 =================
__global__ __launch_bounds__(256) void k_enc2(
    const float* __restrict__ gamma1, const float* __restrict__ beta1,
    const float* __restrict__ w2, const float* __restrict__ b2, float* __restrict__ ws) {
  __shared__ float w2T[64 * 33];
  __shared__ float red[128];
  __shared__ float sc1[64], sh1[64];
  __shared__ float h1b[16][64];
  __shared__ float hb2[16][32];
  float* slots1 = ws + O_SLOTS1;
  float* slots2 = ws + O_SLOTS2;
  float* h1raw  = ws + O_H1RAW;
  float* h2raw  = ws + O_H2RAW;
  int bk = blockIdx.x, t = threadIdx.x;
  int R0 = bk * 16;
  for (int i = t; i < 2048; i += 256) { int j = i >> 6, k = i & 63; w2T[k * 33 + j] = w2[i]; }
  if (t < 128) {
    float s = 0.f;
    for (int b = 0; b < 64; ++b) s += slots1[b * 128 + t];
    red[t] = s;
  }
  __syncthreads();
  if (t < 64) {
    float m = red[t] * (1.f / 1024.f);
    float v = red[64 + t] * (1.f / 1024.f) - m * m;
    float sc = gamma1[t] * rsqrtf(v + EPSBN);
    sc1[t] = sc; sh1[t] = beta1[t] - m * sc;
  }
  __syncthreads();
#pragma unroll
  for (int i = 0; i < 4; ++i) {
    int idx = t + i * 256;
    int r = idx >> 6, k = idx & 63;
    h1b[r][k] = fmaxf(fmaf(h1raw[(size_t)(R0 + r) * 64 + k], sc1[k], sh1[k]), 0.f);
  }
  __syncthreads();
#pragma unroll
  for (int i = 0; i < 2; ++i) {
    int o = t + i * 256;
    int r = o >> 5, j = o & 31;
    float acc = b2[j];
    for (int k = 0; k < 64; ++k) acc = fmaf(h1b[r][k], w2T[k * 33 + j], acc);
    hb2[r][j] = acc;
    h2raw[(size_t)(R0 + r) * 32 + j] = acc;
  }
  __syncthreads();
  if (t < 32) {
    float s = 0.f, q = 0.f;
    for (int r = 0; r < 16; ++r) { float v = hb2[r][t]; s += v; q += v * v; }
    slots2[bk * 64 + t] = s;
    slots2[bk * 64 + 32 + t] = q;
  }
}

// ================= gate: reduce stats2, bn2, gating MLP -> bc =================
__global__ __launch_bounds__(256) void k_gate(
    const float* __restrict__ gamma2, const float* __restrict__ beta2,
    const float* __restrict__ gw1, const float* __restrict__ gb1,
    const float* __restrict__ gw2, const float* __restrict__ gb2,
    const float* __restrict__ gw3, const float* __restrict__ gb3,
    float* __restrict__ ws) {
  __shared__ float red2[64], sc2[32], sh2[32];
  __shared__ float lat[16][32];
  __shared__ float gw1L[64 * 33], gw2L[64 * 65], gw3L[8 * 65];
  __shared__ float gb1L[64], gb2L[64], gb3L[8];
  __shared__ float g1[16][64], g2[16][64];
  float* slots2 = ws + O_SLOTS2;
  float* bcg    = ws + O_BCG;
  float* h2raw  = ws + O_H2RAW;
  int bk = blockIdx.x, t = threadIdx.x;
  int wv = t >> 6, l = t & 63;
  int R0 = bk * 16;
  for (int i = t; i < 2048; i += 256) { int j = i >> 5, k = i & 31; gw1L[j * 33 + k] = gw1[i]; }
  for (int i = t; i < 4096; i += 256) { int j = i >> 6, k = i & 63; gw2L[j * 65 + k] = gw2[i]; }
  for (int i = t; i < 512; i += 256) { int j = i >> 6, k = i & 63; gw3L[j * 65 + k] = gw3[i]; }
  if (t < 64) { gb1L[t] = gb1[t]; gb2L[t] = gb2[t]; }
  if (t < 8) gb3L[t] = gb3[t];
  if (t < 64) {
    float s = 0.f;
    for (int b = 0; b < 64; ++b) s += slots2[b * 64 + t];
    red2[t] = s;
  }
  __syncthreads();
  if (t < 32) {
    float m = red2[t] * (1.f / 1024.f);
    float v = red2[32 + t] * (1.f / 1024.f) - m * m;
    float sc = gamma2[t] * rsqrtf(v + EPSBN);
    sc2[t] = sc; sh2[t] = beta2[t] - m * sc;
  }
  __syncthreads();
#pragma unroll
  for (int i = 0; i < 2; ++i) {
    int idx = t + i * 256;
    int r = idx >> 5, cc = idx & 31;
    lat[r][cc] = fmaxf(fmaf(h2raw[(size_t)(R0 + r) * 32 + cc], sc2[cc], sh2[cc]), 0.f);
  }
  __syncthreads();
#pragma unroll
  for (int rr = 0; rr < 4; ++rr) {
    int r = wv * 4 + rr;
    float a1 = gb1L[l];
    for (int k = 0; k < 32; ++k) a1 = fmaf(gw1L[l * 33 + k], lat[r][k], a1);
    g1[r][l] = eluf(a1);
  }
  __syncthreads();
#pragma unroll
  for (int rr = 0; rr < 4; ++rr) {
    int r = wv * 4 + rr;
    float a2 = gb2L[l];
    for (int k = 0; k < 64; ++k) a2 = fmaf(gw2L[l * 65 + k], g1[r][k], a2);
    g2[r][l] = eluf(a2);
  }
  __syncthreads();
#pragma unroll
  for (int rr = 0; rr < 4; ++rr) {
    int r = wv * 4 + rr;
    if (l < 8) {
      float a3 = gb3L[l];
      for (int k = 0; k < 64; ++k) a3 = fmaf(gw3L[l * 65 + k], g2[r][k], a3);
      float mx = a3;
      mx = fmaxf(mx, __shfl_xor(mx, 1));
      mx = fmaxf(mx, __shfl_xor(mx, 2));
      mx = fmaxf(mx, __shfl_xor(mx, 4));
      float p = expf(a3 - mx);
      float sp = p;
      sp += __shfl_xor(sp, 1); sp += __shfl_xor(sp, 2); sp += __shfl_xor(sp, 4);
      bcg[(size_t)(R0 + r) * 8 + l] = p / sp;
    }
  }
}

// ================= gen1: p[e] = xs @ ew1_e   (grid 64 x 8, bf16x3) =================
__global__ __launch_bounds__(256) void k_gen1(float* __restrict__ ws) {
  int bk = blockIdx.x, e = blockIdx.y, t = threadIdx.x;
  int wv = t >> 6, l = t & 63, c = l & 15, quad = l >> 4;
  const ushort_t* XsH = (const ushort_t*)(ws + O_XSH);
  const ushort_t* XsL = (const ushort_t*)(ws + O_XSL);
  const ushort_t* E1H = (const ushort_t*)(ws + O_E1H);
  const ushort_t* E1L = (const ushort_t*)(ws + O_E1L);
  float* p = ws + O_P;
  f32x4 acc[4] = {};
#pragma unroll
  for (int kc = 0; kc < 4; ++kc) {
    bf16x8 ah = *(const bf16x8*)(XsH + ((size_t)bk * 4 + kc) * 512 + l * 8);
    bf16x8 al = *(const bf16x8*)(XsL + ((size_t)bk * 4 + kc) * 512 + l * 8);
#pragma unroll
    for (int nsi = 0; nsi < 4; ++nsi) {
      int ns = wv * 4 + nsi;
      size_t bo = (((size_t)(e * 16 + ns)) * 4 + kc) * 512 + l * 8;
      bf16x8 bh = *(const bf16x8*)(E1H + bo);
      bf16x8 bl = *(const bf16x8*)(E1L + bo);
      acc[nsi] = MFMA(ah, bh, acc[nsi], 0, 0, 0);
      acc[nsi] = MFMA(al, bh, acc[nsi], 0, 0, 0);
      acc[nsi] = MFMA(ah, bl, acc[nsi], 0, 0, 0);
    }
  }
  float* pe = p + (size_t)e * 262144;
#pragma unroll
  for (int nsi = 0; nsi < 4; ++nsi) {
    int col = (wv * 4 + nsi) * 16 + c;
#pragma unroll
    for (int r = 0; r < 4; ++r)
      pe[(size_t)(bk * 16 + quad * 4 + r) * 256 + col] = acc[nsi][r];
  }
}

// ================= gen2: p[e] = a1 @ ew2_e   (grid 64 x 8, B hi only) =================
__global__ __launch_bounds__(256) void k_gen2(float* __restrict__ ws) {
  int bk = blockIdx.x, e = blockIdx.y, t = threadIdx.x;
  int wv = t >> 6, l = t & 63, c = l & 15, quad = l >> 4;
  const ushort_t* AH = (const ushort_t*)(ws + O_A1H);
  const ushort_t* AL = (const ushort_t*)(ws + O_A1L);
  const ushort_t* E2H = (const ushort_t*)(ws + O_E2H);
  float* p = ws + O_P;
  f32x4 acc[4] = {};
#pragma unroll
  for (int kc = 0; kc < 8; ++kc) {
    bf16x8 ah = *(const bf16x8*)(AH + ((size_t)bk * 8 + kc) * 512 + l * 8);
    bf16x8 al = *(const bf16x8*)(AL + ((size_t)bk * 8 + kc) * 512 + l * 8);
#pragma unroll
    for (int nsi = 0; nsi < 4; ++nsi) {
      int ns = wv * 4 + nsi;
      size_t bo = (((size_t)(e * 16 + ns)) * 8 + kc) * 512 + l * 8;
      bf16x8 bh = *(const bf16x8*)(E2H + bo);
      acc[nsi] = MFMA(ah, bh, acc[nsi], 0, 0, 0);
      acc[nsi] = MFMA(al, bh, acc[nsi], 0, 0, 0);
    }
  }
  float* pe = p + (size_t)e * 262144;
#pragma unroll
  for (int nsi = 0; nsi < 4; ++nsi) {
    int col = (wv * 4 + nsi) * 16 + c;
#pragma unroll
    for (int r = 0; r < 4; ++r)
      pe[(size_t)(bk * 16 + quad * 4 + r) * 256 + col] = acc[nsi][r];
  }
}

// ================= gen3: p3[e] = a2 @ ew3_e   (grid 64 x 2, B hi only) =================
__global__ __launch_bounds__(256) void k_gen3(float* __restrict__ ws) {
  int bk = blockIdx.x, eg = blockIdx.y, t = threadIdx.x;
  int wv = t >> 6, l = t & 63, c = l & 15, quad = l >> 4;
  int e = eg * 4 + wv;
  const ushort_t* AH = (const ushort_t*)(ws + O_A2H);
  const ushort_t* AL = (const ushort_t*)(ws + O_A2L);
  const ushort_t* E3H = (const ushort_t*)(ws + O_E3H);
  float* p3 = ws + O_P;
  f32x4 acc[4] = {};
#pragma unroll
  for (int kc = 0; kc < 8; ++kc) {
    bf16x8 ah = *(const bf16x8*)(AH + ((size_t)bk * 8 + kc) * 512 + l * 8);
    bf16x8 al = *(const bf16x8*)(AL + ((size_t)bk * 8 + kc) * 512 + l * 8);
#pragma unroll
    for (int nsi = 0; nsi < 4; ++nsi) {
      size_t bo = (((size_t)(e * 4 + nsi)) * 8 + kc) * 512 + l * 8;
      bf16x8 bh = *(const bf16x8*)(E3H + bo);
      acc[nsi] = MFMA(ah, bh, acc[nsi], 0, 0, 0);
      acc[nsi] = MFMA(al, bh, acc[nsi], 0, 0, 0);
    }
  }
  float* pe = p3 + (size_t)e * 65536;
#pragma unroll
  for (int nsi = 0; nsi < 4; ++nsi) {
    int col = nsi * 16 + c;
#pragma unroll
    for (int r = 0; r < 4; ++r)
      pe[(size_t)(bk * 16 + quad * 4 + r) * 64 + col] = acc[nsi][r];
  }
}

// ================= comb1/2: A = elu(sum_e bc*(p+eb)) -> fragment planes =================
__global__ __launch_bounds__(256) void k_comb(const float* __restrict__ eb,
    float* __restrict__ ws, int dstH, int dstL) {
  int gid = blockIdx.x * 256 + threadIdx.x;     // 32768: [64 msub][8 kc][64 l2]
  int l2 = gid & 63, kc = (gid >> 6) & 7, msub = gid >> 9;
  int b = msub * 16 + (l2 & 15);
  int k0 = kc * 32 + (l2 >> 4) * 8;
  const float* p = ws + O_P;
  const float* bc = ws + O_BCG;
  unsigned short* ah = (unsigned short*)(ws + dstH);
  unsigned short* al = (unsigned short*)(ws + dstL);
  float wv[NE];
#pragma unroll
  for (int e = 0; e < NE; ++e) wv[e] = bc[b * NE + e];
  float s[8] = {};
#pragma unroll
  for (int e = 0; e < NE; ++e) {
    const float* pr = p + (size_t)e * 262144 + (size_t)b * HH + k0;
    float4 p0 = *(const float4*)pr, p1 = *(const float4*)(pr + 4);
    const float* er = eb + e * HH + k0;
    float4 e0 = *(const float4*)er, e1 = *(const float4*)(er + 4);
    s[0] = fmaf(wv[e], p0.x + e0.x, s[0]);
    s[1] = fmaf(wv[e], p0.y + e0.y, s[1]);
    s[2] = fmaf(wv[e], p0.z + e0.z, s[2]);
    s[3] = fmaf(wv[e], p0.w + e0.w, s[3]);
    s[4] = fmaf(wv[e], p1.x + e1.x, s[4]);
    s[5] = fmaf(wv[e], p1.y + e1.y, s[5]);
    s[6] = fmaf(wv[e], p1.z + e1.z, s[6]);
    s[7] = fmaf(wv[e], p1.w + e1.w, s[7]);
  }
  us8 H, L;
#pragma unroll
  for (int j = 0; j < 8; ++j) {
    float v = eluf(s[j]);
    unsigned short h, lo; split_bf16(v, h, lo);
    H[j] = h; L[j] = lo;
  }
  *(us8*)(ah + (size_t)gid * 8) = H;
  *(us8*)(al + (size_t)gid * 8) = L;
}

// ================= comb3: out = sum_e bc*(p3+eb3) =================
__global__ __launch_bounds__(256) void k_comb3(const float* __restrict__ eb3,
    float* __restrict__ ws, float* __restrict__ out) {
  int gid = blockIdx.x * 256 + threadIdx.x;   // 65536 = 1024 x 64
  int b = gid >> 6, o = gid & 63;
  if (o >= DOUT) return;
  const float* p3 = ws + O_P;
  const float* bc = ws + O_BCG;
  float s = 0.f;
#pragma unroll
  for (int e = 0; e < NE; ++e)
    s = fmaf(bc[b * NE + e], p3[(size_t)e * 65536 + (size_t)b * 64 + o] + eb3[e * DOUT + o], s);
  out[(size_t)b * DOUT + o] = s;
}

extern "C" void kernel_launch(void* const* d_in, const int* in_sizes, int n_in,
                              void* d_out, int out_size, void* d_ws, size_t ws_size,
                              hipStream_t stream) {
  const float* x      = (const float*)d_in[0];
  const float* w1     = (const float*)d_in[1];
  const float* b1     = (const float*)d_in[2];
  const float* gamma1 = (const float*)d_in[3];
  const float* beta1  = (const float*)d_in[4];
  const float* w2     = (const float*)d_in[5];
  const float* b2     = (const float*)d_in[6];
  const float* gamma2 = (const float*)d_in[7];
  const float* beta2  = (const float*)d_in[8];
  const float* gw1    = (const float*)d_in[9];
  const float* gb1    = (const float*)d_in[10];
  const float* gw2    = (const float*)d_in[11];
  const float* gb2    = (const float*)d_in[12];
  const float* gw3    = (const float*)d_in[13];
  const float* gb3    = (const float*)d_in[14];
  const float* ew1    = (const float*)d_in[15];
  const float* eb1    = (const float*)d_in[16];
  const float* ew2    = (const float*)d_in[17];
  const float* eb2    = (const float*)d_in[18];
  const float* ew3    = (const float*)d_in[19];
  const float* eb3    = (const float*)d_in[20];
  float* wsf  = (float*)d_ws;
  float* outp = (float*)d_out;

  k_prep<<<516, 256, 0, stream>>>(x, w1, ew1, ew2, ew3, wsf);
  k_enc1<<<64, 256, 0, stream>>>(b1, wsf);
  k_enc2<<<64, 256, 0, stream>>>(gamma1, beta1, w2, b2, wsf);
  k_gate<<<64, 256, 0, stream>>>(gamma2, beta2, gw1, gb1, gw2, gb2, gw3, gb3, wsf);
  k_gen1<<<dim3(64, 8), 256, 0, stream>>>(wsf);
  k_comb<<<128, 256, 0, stream>>>(eb1, wsf, O_A1H, O_A1L);
  k_gen2<<<dim3(64, 8), 256, 0, stream>>>(wsf);
  k_comb<<<128, 256, 0, stream>>>(eb2, wsf, O_A2H, O_A2L);
  k_gen3<<<dim3(64, 2), 256, 0, stream>>>(wsf);
  k_comb3<<<256, 256, 0, stream>>>(eb3, wsf, outp);
}

// Round 10
// 158.621 us; speedup vs baseline: 1.1735x; 1.0091x over previous
//
#include <hip/hip_runtime.h>
#include <math.h>

// Network_22892175688023 — round 10: 7 stages. R9 numerics (abs 3.9e-3) untouched.
//   K1 k_prep_enc1 : E-planes (E1 hi+lo, E2/E3 hi) + Xs frags + enc L1 VALU (576 blk, LDS union)
//   K2 k_enc2      : reduce slots1, bn1+relu, enc L2, slots2            (64 blk)
//   K3 k_gen1_gate : gen1 p[e] (512 blk) + gating MLP -> bc (64 blk)
//   K4 k_comb1     : A1 = elu(sum_e bc*(p+eb1)) -> fragment planes      (128 blk)
//   K5 k_gen2      : p[e] = a1 @ ew2_e  (B hi only)                     (64x8 blk)
//   K6 k_comb2     : A2 planes                                          (128 blk)
//   K7 k_gen3c     : gen3 (8 waves = 8 experts, raw partials in LDS) +
//                    cross-wave reduce w/ bc+eb3 -> out                 (64 blk x 512)

#define DIN 103
#define NE  8
#define HH  256
#define DOUT 51
#define EPSBN 1e-5f

typedef __attribute__((ext_vector_type(8))) short bf16x8;
typedef __attribute__((ext_vector_type(4))) float f32x4;
typedef __attribute__((ext_vector_type(8))) unsigned short us8;
typedef unsigned short ushort_t;

__device__ __forceinline__ float eluf(float v) { return v > 0.f ? v : (expf(v) - 1.f); }
__device__ __forceinline__ unsigned short bf16h(float f) {
  unsigned u = __float_as_uint(f);
  u += 0x7FFFu + ((u >> 16) & 1u);
  return (unsigned short)(u >> 16);
}
__device__ __forceinline__ float bf16f(unsigned short h) { return __uint_as_float(((unsigned)h) << 16); }
__device__ __forceinline__ void split_bf16(float v, unsigned short& h, unsigned short& l) {
  h = bf16h(v);
  l = bf16h(v - bf16f(h));
}
#define MFMA __builtin_amdgcn_mfma_f32_16x16x32_bf16

// ---- ws layout (float offsets) ----
#define O_SLOTS1 0        // [64][128]
#define O_SLOTS2 8192     // [64][64]
#define O_BCG    12288    // [1024][8]
#define O_H1RAW  20480    // [1024][64]
#define O_H2RAW  86016    // [1024][32]
#define O_XSH    118784   // [64 msub][4 kc][512] sh
#define O_XSL    184320
#define O_E1H    258048   // [8 e][16 ns][4 kc][512] sh
#define O_E1L    389120
#define O_E2H    520192   // [8 e][16 ns][8 kc][512] sh  (hi only)
#define O_E3H    782336   // [8 e][4 ns][8 kc][512] sh   (hi only)
#define O_A1H    847872   // [64 msub][8 kc][512] sh
#define O_A1L    978944
#define O_A2H    1110016
#define O_A2L    1241088
#define O_P      1372160  // [8][1024][256] f32

// ================= K1: prep planes + Xs frags + enc L1 (VALU) =================
// blocks: E2 0..255 | E1 256..383 | E3 384..447 | Xs 448..511 | enc1 512..575
__global__ __launch_bounds__(256) void k_prep_enc1(
    const float* __restrict__ x, const float* __restrict__ w1, const float* __restrict__ b1,
    const float* __restrict__ ew1, const float* __restrict__ ew2, const float* __restrict__ ew3,
    float* __restrict__ ws) {
  __shared__ union {
    float tile[32][65];
    float xt[16][104];
    struct { float w1L[64 * DIN]; float xr[16][104]; float hb[16][64]; } e1;
  } sm;
  int bk = blockIdx.x, t = threadIdx.x;
  int l2 = t & 63, c = l2 & 15, q = l2 >> 4;

  if (bk < 256) {          // ---- E2: K=256, N=256, hi only ----
    int nh = bk & 3, kc = (bk >> 2) & 7, e = bk >> 5;
    int k0 = kc * 32, n0 = nh * 64;
#pragma unroll
    for (int i = 0; i < 8; ++i) {
      int kl = (t >> 6) + i * 4;
      sm.tile[kl][t & 63] = ew2[((size_t)e * HH + k0 + kl) * HH + n0 + (t & 63)];
    }
    __syncthreads();
    int nsl = t >> 6;
    us8 H8;
#pragma unroll
    for (int j = 0; j < 8; ++j) H8[j] = bf16h(sm.tile[q * 8 + j][nsl * 16 + c]);
    size_t dst = (((size_t)(e * 16 + nh * 4 + nsl)) * 8 + kc) * 512 + l2 * 8;
    *(us8*)((ushort_t*)(ws + O_E2H) + dst) = H8;
  } else if (bk < 384) {   // ---- E1: K=103->128, N=256, hi+lo ----
    int b2 = bk - 256;
    int nh = b2 & 3, kc = (b2 >> 2) & 3, e = b2 >> 4;
    int k0 = kc * 32, n0 = nh * 64;
#pragma unroll
    for (int i = 0; i < 8; ++i) {
      int kl = (t >> 6) + i * 4;
      int k = k0 + kl;
      sm.tile[kl][t & 63] = (k < DIN) ? ew1[((size_t)e * DIN + k) * HH + n0 + (t & 63)] : 0.f;
    }
    __syncthreads();
    int nsl = t >> 6;
    us8 H8, L8;
#pragma unroll
    for (int j = 0; j < 8; ++j) {
      unsigned short h, lo; split_bf16(sm.tile[q * 8 + j][nsl * 16 + c], h, lo);
      H8[j] = h; L8[j] = lo;
    }
    size_t dst = (((size_t)(e * 16 + nh * 4 + nsl)) * 4 + kc) * 512 + l2 * 8;
    *(us8*)((ushort_t*)(ws + O_E1H) + dst) = H8;
    *(us8*)((ushort_t*)(ws + O_E1L) + dst) = L8;
  } else if (bk < 448) {   // ---- E3: K=256, N=51->64, hi only ----
    int b2 = bk - 384;
    int kc = b2 & 7, e = b2 >> 3;
    int k0 = kc * 32;
#pragma unroll
    for (int i = 0; i < 8; ++i) {
      int kl = (t >> 6) + i * 4;
      int n = t & 63;
      sm.tile[kl][n] = (n < DOUT) ? ew3[((size_t)e * HH + k0 + kl) * DOUT + n] : 0.f;
    }
    __syncthreads();
    int nsl = t >> 6;
    us8 H8;
#pragma unroll
    for (int j = 0; j < 8; ++j) H8[j] = bf16h(sm.tile[q * 8 + j][nsl * 16 + c]);
    size_t dst = (((size_t)(e * 4 + nsl)) * 8 + kc) * 512 + l2 * 8;
    *(us8*)((ushort_t*)(ws + O_E3H) + dst) = H8;
  } else if (bk < 512) {   // ---- Xs: A-fragments of scaled x, 16 rows/block, hi+lo ----
    int msub = bk - 448;
    for (int i = t; i < 16 * 104; i += 256) {
      int b = i / 104, k = i - b * 104;
      float v = 0.f;
      if (k < DIN) { v = x[(size_t)(msub * 16 + b) * DIN + k]; if (k >= 100) v *= 100.f; }
      sm.xt[b][k] = v;
    }
    __syncthreads();
    int kc = t >> 6;
    int m = c;
    us8 H8, L8;
#pragma unroll
    for (int j = 0; j < 8; ++j) {
      int k = kc * 32 + q * 8 + j;
      float v = (k < 104) ? sm.xt[m][k] : 0.f;
      unsigned short h, lo; split_bf16(v, h, lo);
      H8[j] = h; L8[j] = lo;
    }
    size_t dst = ((size_t)msub * 4 + kc) * 512 + l2 * 8;
    *(us8*)((ushort_t*)(ws + O_XSH) + dst) = H8;
    *(us8*)((ushort_t*)(ws + O_XSL) + dst) = L8;
  } else {                 // ---- enc L1 (VALU): 16 rows/block ----
    float* slots1 = ws + O_SLOTS1;
    float* h1raw  = ws + O_H1RAW;
    int bkl = bk - 512;
    int r0 = bkl * 16;
    for (int i = t; i < 64 * DIN; i += 256) sm.e1.w1L[i] = w1[i];
    for (int i = t; i < 16 * 104; i += 256) {
      int r = i / 104, c2 = i - r * 104;
      float v = 0.f;
      if (c2 < DIN) { v = x[(size_t)(r0 + r) * DIN + c2]; if (c2 >= 100) v *= 100.f; }
      sm.e1.xr[r][c2] = v;
    }
    __syncthreads();
#pragma unroll
    for (int i = 0; i < 4; ++i) {
      int idx = t + i * 256;
      int r = idx >> 6, j = idx & 63;
      float acc = b1[j];
      for (int k = 0; k < DIN; ++k) acc = fmaf(sm.e1.xr[r][k], sm.e1.w1L[j * DIN + k], acc);
      sm.e1.hb[r][j] = acc;
      h1raw[(size_t)(r0 + r) * 64 + j] = acc;
    }
    __syncthreads();
    if (t < 64) {
      float s = 0.f, qq = 0.f;
      for (int r = 0; r < 16; ++r) { float v = sm.e1.hb[r][t]; s += v; qq += v * v; }
      slots1[bkl * 128 + t] = s;
      slots1[bkl * 128 + 64 + t] = qq;
    }
  }
}

// ================= K2: reduce stats1, bn1+relu, enc L2 (VALU), slots2 =================
__global__ __launch_bounds__(256) void k_enc2(
    const float* __restrict__ gamma1, const float* __restrict__ beta1,
    const float* __restrict__ w2, const float* __restrict__ b2, float* __restrict__ ws) {
  __shared__ float w2T[64 * 33];
  __shared__ float red[128];
  __shared__ float sc1[64], sh1[64];
  __shared__ float h1b[16][64];
  __shared__ float hb2[16][32];
  float* slots1 = ws + O_SLOTS1;
  float* slots2 = ws + O_SLOTS2;
  float* h1raw  = ws + O_H1RAW;
  float* h2raw  = ws + O_H2RAW;
  int bk = blockIdx.x, t = threadIdx.x;
  int R0 = bk * 16;
  for (int i = t; i < 2048; i += 256) { int j = i >> 6, k = i & 63; w2T[k * 33 + j] = w2[i]; }
  if (t < 128) {
    float s = 0.f;
    for (int b = 0; b < 64; ++b) s += slots1[b * 128 + t];
    red[t] = s;
  }
  __syncthreads();
  if (t < 64) {
    float m = red[t] * (1.f / 1024.f);
    float v = red[64 + t] * (1.f / 1024.f) - m * m;
    float sc = gamma1[t] * rsqrtf(v + EPSBN);
    sc1[t] = sc; sh1[t] = beta1[t] - m * sc;
  }
  __syncthreads();
#pragma unroll
  for (int i = 0; i < 4; ++i) {
    int idx = t + i * 256;
    int r = idx >> 6, k = idx & 63;
    h1b[r][k] = fmaxf(fmaf(h1raw[(size_t)(R0 + r) * 64 + k], sc1[k], sh1[k]), 0.f);
  }
  __syncthreads();
#pragma unroll
  for (int i = 0; i < 2; ++i) {
    int o = t + i * 256;
    int r = o >> 5, j = o & 31;
    float acc = b2[j];
    for (int k = 0; k < 64; ++k) acc = fmaf(h1b[r][k], w2T[k * 33 + j], acc);
    hb2[r][j] = acc;
    h2raw[(size_t)(R0 + r) * 32 + j] = acc;
  }
  __syncthreads();
  if (t < 32) {
    float s = 0.f, q = 0.f;
    for (int r = 0; r < 16; ++r) { float v = hb2[r][t]; s += v; q += v * v; }
    slots2[bk * 64 + t] = s;
    slots2[bk * 64 + 32 + t] = q;
  }
}

// ================= K3: gen1 p[e] (blocks 0-511) + gate -> bcg (512-575) =================
__global__ __launch_bounds__(256) void k_gen1_gate(
    const float* __restrict__ gamma2, const float* __restrict__ beta2,
    const float* __restrict__ gw1, const float* __restrict__ gb1,
    const float* __restrict__ gw2, const float* __restrict__ gb2,
    const float* __restrict__ gw3, const float* __restrict__ gb3,
    float* __restrict__ ws) {
  int blk = blockIdx.x, t = threadIdx.x;
  int wv = t >> 6, l = t & 63;
  if (blk < 512) {          // ---- gen1: p[e] = xs @ ew1_e (bf16x3) ----
    int bk = blk >> 3, e = blk & 7;
    int c = l & 15, quad = l >> 4;
    const ushort_t* XsH = (const ushort_t*)(ws + O_XSH);
    const ushort_t* XsL = (const ushort_t*)(ws + O_XSL);
    const ushort_t* E1H = (const ushort_t*)(ws + O_E1H);
    const ushort_t* E1L = (const ushort_t*)(ws + O_E1L);
    float* p = ws + O_P;
    f32x4 acc[4] = {};
#pragma unroll
    for (int kc = 0; kc < 4; ++kc) {
      bf16x8 ah = *(const bf16x8*)(XsH + ((size_t)bk * 4 + kc) * 512 + l * 8);
      bf16x8 al = *(const bf16x8*)(XsL + ((size_t)bk * 4 + kc) * 512 + l * 8);
#pragma unroll
      for (int nsi = 0; nsi < 4; ++nsi) {
        int ns = wv * 4 + nsi;
        size_t bo = (((size_t)(e * 16 + ns)) * 4 + kc) * 512 + l * 8;
        bf16x8 bh = *(const bf16x8*)(E1H + bo);
        bf16x8 bl = *(const bf16x8*)(E1L + bo);
        acc[nsi] = MFMA(ah, bh, acc[nsi], 0, 0, 0);
        acc[nsi] = MFMA(al, bh, acc[nsi], 0, 0, 0);
        acc[nsi] = MFMA(ah, bl, acc[nsi], 0, 0, 0);
      }
    }
    float* pe = p + (size_t)e * 262144;
#pragma unroll
    for (int nsi = 0; nsi < 4; ++nsi) {
      int col = (wv * 4 + nsi) * 16 + c;
#pragma unroll
      for (int r = 0; r < 4; ++r)
        pe[(size_t)(bk * 16 + quad * 4 + r) * 256 + col] = acc[nsi][r];
    }
  } else {                  // ---- gate: bn2 + gating MLP -> bcg ----
    __shared__ float red2[64], sc2[32], sh2[32];
    __shared__ float lat[16][32];
    __shared__ float gw1L[64 * 33], gw2L[64 * 65], gw3L[8 * 65];
    __shared__ float gb1L[64], gb2L[64], gb3L[8];
    __shared__ float g1[16][64], g2[16][64];
    float* slots2 = ws + O_SLOTS2;
    float* bcg    = ws + O_BCG;
    float* h2raw  = ws + O_H2RAW;
    int bk = blk - 512;
    int R0 = bk * 16;
    for (int i = t; i < 2048; i += 256) { int j = i >> 5, k = i & 31; gw1L[j * 33 + k] = gw1[i]; }
    for (int i = t; i < 4096; i += 256) { int j = i >> 6, k = i & 63; gw2L[j * 65 + k] = gw2[i]; }
    for (int i = t; i < 512; i += 256) { int j = i >> 6, k = i & 63; gw3L[j * 65 + k] = gw3[i]; }
    if (t < 64) { gb1L[t] = gb1[t]; gb2L[t] = gb2[t]; }
    if (t < 8) gb3L[t] = gb3[t];
    if (t < 64) {
      float s = 0.f;
      for (int b = 0; b < 64; ++b) s += slots2[b * 64 + t];
      red2[t] = s;
    }
    __syncthreads();
    if (t < 32) {
      float m = red2[t] * (1.f / 1024.f);
      float v = red2[32 + t] * (1.f / 1024.f) - m * m;
      float sc = gamma2[t] * rsqrtf(v + EPSBN);
      sc2[t] = sc; sh2[t] = beta2[t] - m * sc;
    }
    __syncthreads();
#pragma unroll
    for (int i = 0; i < 2; ++i) {
      int idx = t + i * 256;
      int r = idx >> 5, cc = idx & 31;
      lat[r][cc] = fmaxf(fmaf(h2raw[(size_t)(R0 + r) * 32 + cc], sc2[cc], sh2[cc]), 0.f);
    }
    __syncthreads();
#pragma unroll
    for (int rr = 0; rr < 4; ++rr) {
      int r = wv * 4 + rr;
      float a1 = gb1L[l];
      for (int k = 0; k < 32; ++k) a1 = fmaf(gw1L[l * 33 + k], lat[r][k], a1);
      g1[r][l] = eluf(a1);
    }
    __syncthreads();
#pragma unroll
    for (int rr = 0; rr < 4; ++rr) {
      int r = wv * 4 + rr;
      float a2 = gb2L[l];
      for (int k = 0; k < 64; ++k) a2 = fmaf(gw2L[l * 65 + k], g1[r][k], a2);
      g2[r][l] = eluf(a2);
    }
    __syncthreads();
#pragma unroll
    for (int rr = 0; rr < 4; ++rr) {
      int r = wv * 4 + rr;
      if (l < 8) {
        float a3 = gb3L[l];
        for (int k = 0; k < 64; ++k) a3 = fmaf(gw3L[l * 65 + k], g2[r][k], a3);
        float mx = a3;
        mx = fmaxf(mx, __shfl_xor(mx, 1));
        mx = fmaxf(mx, __shfl_xor(mx, 2));
        mx = fmaxf(mx, __shfl_xor(mx, 4));
        float p = expf(a3 - mx);
        float sp = p;
        sp += __shfl_xor(sp, 1); sp += __shfl_xor(sp, 2); sp += __shfl_xor(sp, 4);
        bcg[(size_t)(R0 + r) * 8 + l] = p / sp;
      }
    }
  }
}

// ================= K5: gen2 p[e] = a1 @ ew2_e (grid 64 x 8, B hi only) =================
__global__ __launch_bounds__(256) void k_gen2(float* __restrict__ ws) {
  int bk = blockIdx.x, e = blockIdx.y, t = threadIdx.x;
  int wv = t >> 6, l = t & 63, c = l & 15, quad = l >> 4;
  const ushort_t* AH = (const ushort_t*)(ws + O_A1H);
  const ushort_t* AL = (const ushort_t*)(ws + O_A1L);
  const ushort_t* E2H = (const ushort_t*)(ws + O_E2H);
  float* p = ws + O_P;
  f32x4 acc[4] = {};
#pragma unroll
  for (int kc = 0; kc < 8; ++kc) {
    bf16x8 ah = *(const bf16x8*)(AH + ((size_t)bk * 8 + kc) * 512 + l * 8);
    bf16x8 al = *(const bf16x8*)(AL + ((size_t)bk * 8 + kc) * 512 + l * 8);
#pragma unroll
    for (int nsi = 0; nsi < 4; ++nsi) {
      int ns = wv * 4 + nsi;
      size_t bo = (((size_t)(e * 16 + ns)) * 8 + kc) * 512 + l * 8;
      bf16x8 bh = *(const bf16x8*)(E2H + bo);
      acc[nsi] = MFMA(ah, bh, acc[nsi], 0, 0, 0);
      acc[nsi] = MFMA(al, bh, acc[nsi], 0, 0, 0);
    }
  }
  float* pe = p + (size_t)e * 262144;
#pragma unroll
  for (int nsi = 0; nsi < 4; ++nsi) {
    int col = (wv * 4 + nsi) * 16 + c;
#pragma unroll
    for (int r = 0; r < 4; ++r)
      pe[(size_t)(bk * 16 + quad * 4 + r) * 256 + col] = acc[nsi][r];
  }
}

// ================= K4/K6: comb: A = elu(sum_e bc*(p+eb)) -> fragment planes =================
__global__ __launch_bounds__(256) void k_comb(const float* __restrict__ eb,
    float* __restrict__ ws, int dstH, int dstL) {
  int gid = blockIdx.x * 256 + threadIdx.x;     // 32768: [64 msub][8 kc][64 l2]
  int l2 = gid & 63, kc = (gid >> 6) & 7, msub = gid >> 9;
  int b = msub * 16 + (l2 & 15);
  int k0 = kc * 32 + (l2 >> 4) * 8;
  const float* p = ws + O_P;
  const float* bc = ws + O_BCG;
  unsigned short* ah = (unsigned short*)(ws + dstH);
  unsigned short* al = (unsigned short*)(ws + dstL);
  float wv[NE];
#pragma unroll
  for (int e = 0; e < NE; ++e) wv[e] = bc[b * NE + e];
  float s[8] = {};
#pragma unroll
  for (int e = 0; e < NE; ++e) {
    const float* pr = p + (size_t)e * 262144 + (size_t)b * HH + k0;
    float4 p0 = *(const float4*)pr, p1 = *(const float4*)(pr + 4);
    const float* er = eb + e * HH + k0;
    float4 e0 = *(const float4*)er, e1 = *(const float4*)(er + 4);
    s[0] = fmaf(wv[e], p0.x + e0.x, s[0]);
    s[1] = fmaf(wv[e], p0.y + e0.y, s[1]);
    s[2] = fmaf(wv[e], p0.z + e0.z, s[2]);
    s[3] = fmaf(wv[e], p0.w + e0.w, s[3]);
    s[4] = fmaf(wv[e], p1.x + e1.x, s[4]);
    s[5] = fmaf(wv[e], p1.y + e1.y, s[5]);
    s[6] = fmaf(wv[e], p1.z + e1.z, s[6]);
    s[7] = fmaf(wv[e], p1.w + e1.w, s[7]);
  }
  us8 H, L;
#pragma unroll
  for (int j = 0; j < 8; ++j) {
    float v = eluf(s[j]);
    unsigned short h, lo; split_bf16(v, h, lo);
    H[j] = h; L[j] = lo;
  }
  *(us8*)(ah + (size_t)gid * 8) = H;
  *(us8*)(al + (size_t)gid * 8) = L;
}

// ================= K7: gen3 (8 waves = experts) + reduce w/ bc+eb3 -> out =================
__global__ __launch_bounds__(512) void k_gen3c(const float* __restrict__ eb3,
    float* __restrict__ ws, float* __restrict__ out) {
  __shared__ float p3s[8][16][64];   // 32 KB raw per-expert partials
  __shared__ float bcL[16][8];
  __shared__ float eb3L[8][64];
  int bk = blockIdx.x, t = threadIdx.x;
  int wv = t >> 6, l = t & 63, c = l & 15, quad = l >> 4;
  int R0 = bk * 16;
  const ushort_t* AH = (const ushort_t*)(ws + O_A2H);
  const ushort_t* AL = (const ushort_t*)(ws + O_A2L);
  const ushort_t* E3H = (const ushort_t*)(ws + O_E3H);
  const float* bcg = ws + O_BCG;
  if (t < 128) bcL[t >> 3][t & 7] = bcg[(size_t)(R0 + (t >> 3)) * 8 + (t & 7)];
  if (t >= 128 && t < 640 - 128) {   // threads 128..511 cover 8*64=512? no: use all
  }
  {
    int i = t;
    if (i < 512) { int e = i >> 6, n = i & 63; eb3L[e][n] = (n < DOUT) ? eb3[e * DOUT + n] : 0.f; }
  }
  // MFMA: wave wv = expert wv, B hi only (A2 hi+lo)
  int e = wv;
  f32x4 acc[4] = {};
#pragma unroll
  for (int kc = 0; kc < 8; ++kc) {
    bf16x8 ah = *(const bf16x8*)(AH + ((size_t)bk * 8 + kc) * 512 + l * 8);
    bf16x8 al = *(const bf16x8*)(AL + ((size_t)bk * 8 + kc) * 512 + l * 8);
#pragma unroll
    for (int nsi = 0; nsi < 4; ++nsi) {
      size_t bo = (((size_t)(e * 4 + nsi)) * 8 + kc) * 512 + l * 8;
      bf16x8 bh = *(const bf16x8*)(E3H + bo);
      acc[nsi] = MFMA(ah, bh, acc[nsi], 0, 0, 0);
      acc[nsi] = MFMA(al, bh, acc[nsi], 0, 0, 0);
    }
  }
#pragma unroll
  for (int nsi = 0; nsi < 4; ++nsi)
#pragma unroll
    for (int r = 0; r < 4; ++r)
      p3s[e][quad * 4 + r][nsi * 16 + c] = acc[nsi][r];
  __syncthreads();
#pragma unroll
  for (int i = 0; i < 2; ++i) {
    int idx = t + i * 512;               // 1024 outputs: [16 rows][64 cols]
    int row = idx >> 6, col = idx & 63;
    float s = 0.f;
#pragma unroll
    for (int e2 = 0; e2 < 8; ++e2)
      s = fmaf(bcL[row][e2], p3s[e2][row][col] + eb3L[e2][col], s);
    if (col < DOUT) out[(size_t)(R0 + row) * DOUT + col] = s;
  }
}

extern "C" void kernel_launch(void* const* d_in, const int* in_sizes, int n_in,
                              void* d_out, int out_size, void* d_ws, size_t ws_size,
                              hipStream_t stream) {
  const float* x      = (const float*)d_in[0];
  const float* w1     = (const float*)d_in[1];
  const float* b1     = (const float*)d_in[2];
  const float* gamma1 = (const float*)d_in[3];
  const float* beta1  = (const float*)d_in[4];
  const float* w2     = (const float*)d_in[5];
  const float* b2     = (const float*)d_in[6];
  const float* gamma2 = (const float*)d_in[7];
  const float* beta2  = (const float*)d_in[8];
  const float* gw1    = (const float*)d_in[9];
  const float* gb1    = (const float*)d_in[10];
  const float* gw2    = (const float*)d_in[11];
  const float* gb2    = (const float*)d_in[12];
  const float* gw3    = (const float*)d_in[13];
  const float* gb3    = (const float*)d_in[14];
  const float* ew1    = (const float*)d_in[15];
  const float* eb1    = (const float*)d_in[16];
  const float* ew2    = (const float*)d_in[17];
  const float* eb2    = (const float*)d_in[18];
  const float* ew3    = (const float*)d_in[19];
  const float* eb3    = (const float*)d_in[20];
  float* wsf  = (float*)d_ws;
  float* outp = (float*)d_out;

  k_prep_enc1<<<576, 256, 0, stream>>>(x, w1, b1, ew1, ew2, ew3, wsf);
  k_enc2<<<64, 256, 0, stream>>>(gamma1, beta1, w2, b2, wsf);
  k_gen1_gate<<<576, 256, 0, stream>>>(gamma2, beta2, gw1, gb1, gw2, gb2, gw3, gb3, wsf);
  k_comb<<<128, 256, 0, stream>>>(eb1, wsf, O_A1H, O_A1L);
  k_gen2<<<dim3(64, 8), 256, 0, stream>>>(wsf);
  k_comb<<<128, 256, 0, stream>>>(eb2, wsf, O_A2H, O_A2L);
  k_gen3c<<<64, 512, 0, stream>>>(eb3, wsf, outp);
}